// Round 1
// baseline (381.217 us; speedup 1.0000x reference)
//
#include <hip/hip_runtime.h>
#include <hip/hip_bf16.h>
#include <stdint.h>

#define BB 512
#define TT 1024
#define II 15
#define HH 64
#define OO 11

typedef __attribute__((ext_vector_type(8))) short short8;
typedef __attribute__((ext_vector_type(4))) float floatx4;

__device__ __forceinline__ unsigned short f2bf(float f) {
    unsigned int u = __float_as_uint(f);
    u += 0x7fffu + ((u >> 16) & 1u);
    return (unsigned short)(u >> 16);
}

// One wave per batch element. lane = h index (H=64 == wavefront size).
// W_hh row h (64 f32) + W_ih row h (15 f32) live in VGPRs of lane h.
// Per step: broadcast h_prev and x via v_readlane, 79 fmacs, relu, bf16 store.
__global__ __launch_bounds__(64) void rnn_recurrence(
    const float* __restrict__ x, const float* __restrict__ W_ih,
    const float* __restrict__ b_ih, const float* __restrict__ W_hh,
    const float* __restrict__ b_hh, unsigned short* __restrict__ hs,
    float* __restrict__ h_last)
{
    const int b = blockIdx.x;
    const int lane = threadIdx.x;

    float w[HH];
#pragma unroll
    for (int k = 0; k < HH; ++k) w[k] = W_hh[lane * HH + k];
    float wi[II];
#pragma unroll
    for (int i = 0; i < II; ++i) wi[i] = W_ih[lane * II + i];
    const float bias = b_ih[lane] + b_hh[lane];

    const float* xb = x + (size_t)b * TT * II;
    unsigned short* hrow = hs + (size_t)b * TT * HH + lane;

    float h = 0.0f;

    for (int tc = 0; tc < TT; tc += 64) {
        // stage 64 timesteps of x into registers: lane L holds x[b, tc+L, 0..14]
        float xl[II];
#pragma unroll
        for (int i = 0; i < II; ++i) xl[i] = xb[(tc + lane) * II + i];

#pragma unroll 4
        for (int ts = 0; ts < 64; ++ts) {
            float a[4];
            a[0] = bias; a[1] = 0.0f; a[2] = 0.0f; a[3] = 0.0f;
            // input projection: x[b,t,i] broadcast from lane ts
#pragma unroll
            for (int i = 0; i < II; ++i) {
                float xv = __int_as_float(
                    __builtin_amdgcn_readlane(__float_as_int(xl[i]), ts));
                a[i & 3] += xv * wi[i];
            }
            // recurrent GEMV: h_prev[k] broadcast from lane k (constant index)
#pragma unroll
            for (int k = 0; k < HH; ++k) {
                float hv = __int_as_float(
                    __builtin_amdgcn_readlane(__float_as_int(h), k));
                a[k & 3] += hv * w[k];
            }
            h = fmaxf((a[0] + a[1]) + (a[2] + a[3]), 0.0f);
            hrow[(size_t)(tc + ts) * HH] = f2bf(h);
        }
    }
    h_last[b * HH + lane] = h;
}

// Decoder: out[b,t,o] = relu(hs[b,t,:] . W_dec[o,:] + b_dec[o])
// MFMA 16x16x32 bf16: M = 16 consecutive (b,t) rows, N = 16 (11 used), K = 64.
// A-frag: A[m=lane&15][k=quad*8+j] -> 16B contiguous load from hs.
// B-frag: B[k=quad*8+j][n=lane&15] = W_dec[n][k] -> 16B contiguous from LDS.
// C/D: col = lane&15, row = quad*4 + reg.
__global__ __launch_bounds__(256) void rnn_decode(
    const unsigned short* __restrict__ hs, const float* __restrict__ W_dec,
    const float* __restrict__ b_dec, float* __restrict__ out)
{
    __shared__ __align__(16) unsigned short wl[16 * HH];
    const int tid = threadIdx.x;
    for (int i = tid; i < 16 * HH; i += 256) {
        wl[i] = (i < OO * HH) ? f2bf(W_dec[i]) : (unsigned short)0;
    }
    __syncthreads();

    const int lane = tid & 63;
    const int wid  = tid >> 6;
    const int col  = lane & 15;
    const int quad = lane >> 4;
    const float bd = (col < OO) ? b_dec[col] : 0.0f;

    // loop-invariant B fragments
    const unsigned short* wp = &wl[col * HH + quad * 8];
    short8 bf0 = *(const short8*)wp;
    short8 bf1 = *(const short8*)(wp + 32);

    const int gw = blockIdx.x * 4 + wid;   // 4096 waves, 8 tiles each
#pragma unroll 2
    for (int it = 0; it < 8; ++it) {
        const size_t tile = (size_t)gw * 8 + it;
        const size_t btb = tile * 16;
        const unsigned short* ap = hs + (btb + (size_t)col) * HH + quad * 8;
        short8 af0 = *(const short8*)ap;
        short8 af1 = *(const short8*)(ap + 32);
        floatx4 acc = {0.0f, 0.0f, 0.0f, 0.0f};
        acc = __builtin_amdgcn_mfma_f32_16x16x32_bf16(af0, bf0, acc, 0, 0, 0);
        acc = __builtin_amdgcn_mfma_f32_16x16x32_bf16(af1, bf1, acc, 0, 0, 0);
        if (col < OO) {
#pragma unroll
            for (int r = 0; r < 4; ++r) {
                const size_t row = btb + (size_t)(quad * 4 + r);
                out[row * OO + col] = fmaxf(acc[r] + bd, 0.0f);
            }
        }
    }
}

extern "C" void kernel_launch(void* const* d_in, const int* in_sizes, int n_in,
                              void* d_out, int out_size, void* d_ws, size_t ws_size,
                              hipStream_t stream) {
    const float* x     = (const float*)d_in[0];
    const float* W_ih  = (const float*)d_in[1];
    const float* b_ih  = (const float*)d_in[2];
    const float* W_hh  = (const float*)d_in[3];
    const float* b_hh  = (const float*)d_in[4];
    const float* W_dec = (const float*)d_in[5];
    const float* b_dec = (const float*)d_in[6];

    float* out    = (float*)d_out;
    float* h_last = out + (size_t)BB * TT * OO;   // second tuple output
    unsigned short* hs = (unsigned short*)d_ws;   // [B][T][H] bf16, 64 MiB

    rnn_recurrence<<<BB, 64, 0, stream>>>(x, W_ih, b_ih, W_hh, b_hh, hs, h_last);
    rnn_decode<<<1024, 256, 0, stream>>>(hs, W_dec, b_dec, out);
}